// Round 22
// baseline (110.116 us; speedup 1.0000x reference)
//
#include <hip/hip_runtime.h>
#include <hip/hip_bf16.h>

#define NN  512    // data grid / coefficient count per axis
#define NE  1024   // eval points per axis
#define NBC 64     // batch * channels
#define WH  6      // truncated-inverse half width (0.268^7 ~ 1e-4 rel err)
#define WT  13     // 2*WH+1 taps
#define YT  32     // y-tile per eval block

typedef float v4f __attribute__((ext_vector_type(4)));

// ================= compile-time table generation =================
// (derivation unchanged from R21)

struct Tables {
  float Gb[NN][WT];      // truncated A^-1 band (row-major)
  float GbT[WT][NN];     // transposed: GbT[d][i] = Gb[i][d]
  int   espan[NE];
  float ebas[NE * 4];    // y-combine weights (float4-aligned)
  float W3T[12][NE];     // anchored 4-tap x-filter, transposed
  unsigned int smask[NE / YT];  // slide bitmask per y-tile
};

constexpr int cfindspan(double u, const float* t) {
  if (u >= (double)t[NN]) return NN - 1;          // t[512] == 1.0
  int lo = 3, hi = NN - 1;
  while (lo < hi) {
    int mid = (lo + hi + 1) >> 1;
    if ((double)t[mid] <= u) lo = mid; else hi = mid - 1;
  }
  return lo;
}

constexpr void cdeboor4(double u, const float* t, int s, double* N) {
  double left[4] = {}, right[4] = {};
  N[0] = 1.0; N[1] = 0.0; N[2] = 0.0; N[3] = 0.0;
  for (int d = 1; d <= 3; ++d) {
    left[d]  = u - (double)t[s + 1 - d];
    right[d] = (double)t[s + d] - u;
    double saved = 0.0;
    for (int r = 0; r < d; ++r) {
      double temp = N[r] / (right[r + 1] + left[d - r]);
      N[r] = saved + right[r + 1] * temp;
      saved = left[d - r] * temp;
    }
    N[d] = saved;
  }
}

constexpr Tables make_tables() {
  Tables T{};
  float x[NN] = {};
  for (int i = 0; i < NN; ++i) x[i] = (float)(-1.0 + (2.0 * i) / 511.0);
  x[0] = -1.0f; x[NN - 1] = 1.0f;
  float t[NN + 4] = {};
  {
    float cs[NN + 1] = {};
    for (int i = 0; i < NN; ++i) cs[i + 1] = cs[i] + x[i];
    for (int i = 0; i < NN - 4; ++i) t[4 + i] = (cs[4 + i] - cs[1 + i]) / 3.0f;
    for (int i = 0; i < 4; ++i) { t[i] = -1.0f; t[NN + i] = 1.0f; }
  }
  double W[NN][7] = {};
  for (int r = 0; r < NN; ++r) {
    double u = (double)x[r];
    int s = cfindspan(u, t);
    double N[4] = {};
    cdeboor4(u, t, s, N);
    for (int dd = 0; dd < 4; ++dd) W[r][s - r + dd] += N[dd];
  }
  for (int r = 0; r < NN; ++r) {
    double rd = 1.0 / W[r][3];
    for (int k = 1; k <= 3; ++k) {
      if (r + k < NN) {
        double l = W[r + k][3 - k] * rd;
        W[r + k][3 - k] = l;
        for (int cc = 1; cc <= 3; ++cc) W[r + k][3 - k + cc] -= l * W[r][3 + cc];
      }
    }
  }
  // truncated inverse band (half-width WH)
  double Gbd[NN][WT] = {};
  double tv[WT] = {};
  for (int pass = 0; pass < 3; ++pass) {
    const int ylo = (pass == 0) ? 0 : (pass == 1) ? 480 : 256;
    const int yhi = (pass == 0) ? 32 : (pass == 1) ? 512 : 257;
    for (int y = ylo; y < yhi; ++y) {
      double wv[21] = {};
      int rend = y + 20; if (rend > NN - 1) rend = NN - 1;
      wv[0] = 1.0;
      for (int r = y + 1; r <= rend; ++r) {
        double acc = 0.0;
        if (r - 1 >= y) acc += W[r][2] * wv[r - 1 - y];
        if (r - 2 >= y) acc += W[r][1] * wv[r - 2 - y];
        if (r - 3 >= y) acc += W[r][0] * wv[r - 3 - y];
        wv[r - y] = -acc;
      }
      double g[33] = {};
      int glo = y - WH; if (glo < 0) glo = 0;
      for (int r = rend; r >= glo; --r) {
        double acc = (r >= y) ? wv[r - y] : 0.0;
        if (r + 1 <= rend) acc -= W[r][4] * g[r + 1 - (y - WH)];
        if (r + 2 <= rend) acc -= W[r][5] * g[r + 2 - (y - WH)];
        if (r + 3 <= rend) acc -= W[r][6] * g[r + 3 - (y - WH)];
        g[r - (y - WH)] = acc / W[r][3];
      }
      if (pass == 2) {
        for (int d = 0; d < WT; ++d) tv[d] = g[2 * WH - d];   // Ainv[256+WH-d][256]
      } else {
        int jlo = y - WH; if (jlo < 0) jlo = 0;
        int jhi = y + WH; if (jhi > NN - 1) jhi = NN - 1;
        for (int j = jlo; j <= jhi; ++j) {
          const bool bdry = (pass == 0) ? (j < 24) : (j >= 488);
          if (bdry) Gbd[j][y - j + WH] = g[j - (y - WH)];
        }
      }
    }
  }
  for (int j = 24; j < 488; ++j)
    for (int d = 0; d < WT; ++d) Gbd[j][d] = tv[d];
  for (int j = 0; j < NN; ++j)
    for (int d = 0; d < WT; ++d) T.Gb[j][d] = (float)Gbd[j][d];
  for (int d = 0; d < WT; ++d)
    for (int j = 0; j < NN; ++j) T.GbT[d][j] = (float)Gbd[j][d];
  // eval-point basis + anchored transposed 12-tap x-filter
  int    s_all[NE] = {};
  double dN[NE][4] = {};
  for (int i = 0; i < NE; ++i) {
    float xe = (float)(-1.0 + (2.0 * i) / 1023.0);
    if (i == 0) xe = -1.0f;
    if (i == NE - 1) xe = 1.0f;
    double u = (double)xe;
    int s = cfindspan(u, t);
    double N[4] = {};
    cdeboor4(u, t, s, N);
    s_all[i] = s;
    for (int k = 0; k < 4; ++k) dN[i][k] = N[k];
    T.espan[i] = s;
    T.ebas[i * 4 + 0] = (float)N[0];
    T.ebas[i * 4 + 1] = (float)N[1];
    T.ebas[i * 4 + 2] = (float)N[2];
    T.ebas[i * 4 + 3] = (float)N[3];
  }
  // W3T[m][x]: out[x] = sum_m W3T[m][x] * CTrow[a3 + m], a3 = (s_all[quad0]-3)&~3.
  for (int xx = 0; xx < NE; ++xx) {
    const int a3 = (s_all[(xx >> 2) << 2] - 3) & ~3;
    for (int k = 0; k < 4; ++k) {
      const int m = s_all[xx] - 3 + k - a3;
      T.W3T[m][xx] = (float)dN[xx][k];
    }
  }
  // slide bitmask: bit k set iff espan increments at local row k of the tile
  for (int tt = 0; tt < NE / YT; ++tt) {
    unsigned int m = 0u;
    for (int k = 1; k < YT; ++k)
      if (s_all[tt * YT + k] != s_all[tt * YT + k - 1]) m |= (1u << k);
    T.smask[tt] = m;
  }
  return T;
}

__constant__ Tables g_tab = make_tables();

__device__ __forceinline__ unsigned short f2bf(float f) {
  __hip_bfloat16 h = __float2bfloat16(f);              // round-to-nearest-even
  return reinterpret_cast<const unsigned short&>(h);
}

// ------------- K1: 2D banded solve, LDS-STAGED stage 1 -------------
// CT[bc][j][i] (BF16) = sum_{d,e} Gb[i][d]*Gb[j][e]*Z[bc][i-WH+d][j-WH+e]
// Stage 0: cooperative load of the 80x80 Z window into LDS — all 256
// threads issue ~6 back-to-back vector loads, so cold-HBM latency is paid
// ONCE per block (TLP-amortized), not per serial per-thread chain (the
// R21 direct-global version exposed ~900cyc per load group at 3-4
// waves/SIMD). Boundary = granule/row clamp + zero taps, as before.

__global__ __launch_bounds__(256) void k_solve2d(const float* __restrict__ Z,
                                                 unsigned short* __restrict__ CT) {
  const int it = blockIdx.x * 64;
  const int jt = blockIdx.y * 64;
  const int bc = blockIdx.z;
  const float* __restrict__ src = Z + (size_t)bc * (NN * NN);
  __shared__ float in[80][88];   // Z window [i'][j'], 28.2 KB
  __shared__ float At[64][89];   // stage-1 result TRANSPOSED: At[jc][ii], 22.8 KB
  const int tid = threadIdx.x;
  const int q4 = (tid & 15) * 4;    // quad base (jc for stage1, ic for stage2)
  const int iiB = tid >> 4;

  // ---- stage 0: cooperative staging (granule/row clamp; garbage hits zero taps)
  for (int u = tid; u < 80 * 20; u += 256) {
    const int r = u / 20, e = u % 20;
    int gi = it - 8 + r;
    gi = (gi < 0) ? 0 : ((gi > NN - 1) ? NN - 1 : gi);
    int gj = jt - 8 + e * 4;
    gj = (gj < 0) ? 0 : ((gj > NN - 4) ? NN - 4 : gj);
    *(float4*)&in[r][e * 4] = *(const float4*)&src[(size_t)gi * NN + gj];
  }

  { // stage 1: 13-tap along j, 80 i-rows, from LDS
    float cy[4][WT];
    #pragma unroll
    for (int d = 0; d < WT; ++d)
      #pragma unroll
      for (int q = 0; q < 4; ++q)
        cy[q][d] = g_tab.GbT[d][jt + q4 + q];     // lane-coalesced
    __syncthreads();
    #pragma unroll
    for (int p = 0; p < 5; ++p) {
      const int ii = p * 16 + iiB;
      float w[20];
      #pragma unroll
      for (int e = 0; e < 5; ++e)
        *(float4*)&w[e * 4] = *(const float4*)&in[ii][q4 + e * 4];
      float4 a = make_float4(0.f, 0.f, 0.f, 0.f);
      #pragma unroll
      for (int d = 0; d < WT; ++d) {
        a.x += cy[0][d] * w[2 + d];
        a.y += cy[1][d] * w[3 + d];
        a.z += cy[2][d] * w[4 + d];
        a.w += cy[3][d] * w[5 + d];
      }
      At[q4 + 0][ii] = a.x;
      At[q4 + 1][ii] = a.y;
      At[q4 + 2][ii] = a.z;
      At[q4 + 3][ii] = a.w;
    }
  }
  { // stage 2: 13-tap along i from LDS; coalesced bf16 writes
    float cx[4][WT];
    #pragma unroll
    for (int d = 0; d < WT; ++d)
      #pragma unroll
      for (int q = 0; q < 4; ++q)
        cx[q][d] = g_tab.GbT[d][it + q4 + q];     // lane-coalesced
    __syncthreads();
    unsigned short* __restrict__ dst = CT + (size_t)bc * (NN * NN);
    #pragma unroll 1
    for (int p = 0; p < 4; ++p) {
      const int jc = p * 16 + iiB;
      float w[20];
      #pragma unroll
      for (int e = 0; e < 5; ++e)
        *(float4*)&w[e * 4] = *(const float4*)&At[jc][q4 + e * 4];
      float4 a = make_float4(0.f, 0.f, 0.f, 0.f);
      #pragma unroll
      for (int d = 0; d < WT; ++d) {
        a.x += cx[0][d] * w[2 + d];
        a.y += cx[1][d] * w[3 + d];
        a.z += cx[2][d] * w[4 + d];
        a.w += cx[3][d] * w[5 + d];
      }
      ushort4 o;
      o.x = f2bf(a.x); o.y = f2bf(a.y); o.z = f2bf(a.z); o.w = f2bf(a.w);
      *(ushort4*)&dst[(size_t)(jt + jc) * NN + it + q4] = o;   // 8B aligned
    }
  }
}

// ------------- K2: batched-store sliding-P eval (unchanged from R19) -------------

struct Pf { uint2 a, b, c; };

__global__ __launch_bounds__(256) void k_eval11(const unsigned short* __restrict__ CT,
                                                float* __restrict__ out) {
  const int b = blockIdx.x;                         // 32 y-tiles
  const int ytile = ((b & 7) << 2) | (b >> 3);      // XCD-chunked swizzle (bijective, 32)
  const int y0 = ytile * YT;
  const int bc = blockIdx.y;
  const unsigned short* __restrict__ S = CT + (size_t)bc * (NN * NN);
  const int tid = threadIdx.x;

  const int x0 = tid * 4;
  const int a3 = (g_tab.espan[x0] - 3) & ~3;        // window base (mult of 4 -> 8B aligned)
  float tp[4][12];
  #pragma unroll
  for (int m = 0; m < 12; ++m)
    #pragma unroll
    for (int e = 0; e < 4; ++e)
      tp[e][m] = g_tab.W3T[m][x0 + e];

  auto loadRow = [&](int r) -> Pf {
    r = (r > NN - 1) ? NN - 1 : r;                  // clamp (tail prefetches unused)
    const unsigned short* __restrict__ rp = &S[(size_t)r * NN + a3];
    Pf f;
    f.a = *(const uint2*)&rp[0];
    f.b = *(const uint2*)&rp[4];
    f.c = *(const uint2*)&rp[8];
    return f;
  };
  auto filt = [&](Pf f) -> v4f {
    float w[12];
    w[0]  = __uint_as_float(f.a.x << 16); w[1]  = __uint_as_float(f.a.x & 0xffff0000u);
    w[2]  = __uint_as_float(f.a.y << 16); w[3]  = __uint_as_float(f.a.y & 0xffff0000u);
    w[4]  = __uint_as_float(f.b.x << 16); w[5]  = __uint_as_float(f.b.x & 0xffff0000u);
    w[6]  = __uint_as_float(f.b.y << 16); w[7]  = __uint_as_float(f.b.y & 0xffff0000u);
    w[8]  = __uint_as_float(f.c.x << 16); w[9]  = __uint_as_float(f.c.x & 0xffff0000u);
    w[10] = __uint_as_float(f.c.y << 16); w[11] = __uint_as_float(f.c.y & 0xffff0000u);
    v4f p;
    #pragma unroll
    for (int e = 0; e < 4; ++e) {
      float s0 = 0.f, s1 = 0.f;
      #pragma unroll
      for (int m = 0; m < 12; m += 2) {
        s0 += tp[e][m]     * w[m];
        s1 += tp[e][m + 1] * w[m + 1];
      }
      p[e] = s0 + s1;
    }
    return p;
  };

  int prev = g_tab.espan[y0];
  Pf f0 = loadRow(prev - 3), f1 = loadRow(prev - 2),
     f2 = loadRow(prev - 1), f3 = loadRow(prev);
  Pf pfA = loadRow(prev + 1), pfB = loadRow(prev + 2);
  v4f P0 = filt(f0), P1 = filt(f1), P2 = filt(f2), P3 = filt(f3);
  const unsigned int smask = g_tab.smask[ytile];    // SGPR slide schedule

  float* __restrict__ O0 = out + ((size_t)bc * NE + y0) * NE + x0;
  #pragma unroll 1
  for (int bb = 0; bb < YT / 8; ++bb) {
    v4f o[8];
    #pragma unroll
    for (int r = 0; r < 8; ++r) {
      const int k = bb * 8 + r;
      if (smask & (1u << k)) {                      // slide: consume prefetched row
        P0 = P1; P1 = P2; P2 = P3;
        P3 = filt(pfA);
        pfA = pfB;
        prev += 1;
        pfB = loadRow(prev + 2);                    // refill pipeline
      }
      const float4 wy = *(const float4*)&g_tab.ebas[(y0 + k) * 4];
      #pragma unroll
      for (int e = 0; e < 4; ++e)
        o[r][e] = wy.x * P0[e] + wy.y * P1[e] + wy.z * P2[e] + wy.w * P3[e];
    }
    #pragma unroll
    for (int r = 0; r < 8; ++r)
      *(v4f*)&O0[(size_t)(bb * 8 + r) * NE] = o[r]; // burst: hazard once per 8 stores
  }
}

// ---------------- host launcher ----------------

extern "C" void kernel_launch(void* const* d_in, const int* in_sizes, int n_in,
                              void* d_out, int out_size, void* d_ws, size_t ws_size,
                              hipStream_t stream) {
  (void)in_sizes; (void)n_in; (void)out_size; (void)ws_size;
  const float* Z = (const float*)d_in[0];
  float* out = (float*)d_out;
  unsigned short* CT = (unsigned short*)d_ws;   // 32 MB bf16 coefficients

  k_solve2d<<<dim3(8, 8, NBC),    256, 0, stream>>>(Z,  CT);   // LDS-staged 2D banded solve
  k_eval11 <<<dim3(NE / YT, NBC), 256, 0, stream>>>(CT, out);  // batched-store eval
}

// Round 23
// 102.266 us; speedup vs baseline: 1.0768x; 1.0768x over previous
//
#include <hip/hip_runtime.h>
#include <hip/hip_bf16.h>

#define NN  512    // data grid / coefficient count per axis
#define NE  1024   // eval points per axis
#define NBC 64     // batch * channels
#define WH  5      // truncated-inverse half width (0.268^6 ~ 4e-4 rel; R17-proven)
#define WT  11     // 2*WH+1 taps
#define YT  32     // y-tile per eval block

typedef float v4f __attribute__((ext_vector_type(4)));

// ================= compile-time table generation =================
// x = float32 linspace(-1,1,512); knots via float32 cumsum sliding mean;
// basis via de Boor in double; banded LU in double; truncated inverse band
// Gb (half-width 5, R17-proven accuracy); GbT transposed for lane-coalesced
// loads; W8T = 4-tap eval basis re-anchored to a per-quad 2-ALIGNED 8-tap
// window (dword-aligned bf16 loads, max offset proven <= 6), transposed;
// smask = per-y-tile slide bitmask. Gb/W8T have EXACT ZEROS at tap
// positions outside the true span — boundary = clamp + zero taps.

struct Tables {
  float Gb[NN][WT];      // truncated A^-1 band (row-major)
  float GbT[WT][NN];     // transposed: GbT[d][i] = Gb[i][d]
  int   espan[NE];
  float ebas[NE * 4];    // y-combine weights (float4-aligned)
  float W8T[8][NE];      // anchored 4-tap x-filter in 8-window, transposed
  unsigned int smask[NE / YT];  // slide bitmask per y-tile
};

constexpr int cfindspan(double u, const float* t) {
  if (u >= (double)t[NN]) return NN - 1;          // t[512] == 1.0
  int lo = 3, hi = NN - 1;
  while (lo < hi) {
    int mid = (lo + hi + 1) >> 1;
    if ((double)t[mid] <= u) lo = mid; else hi = mid - 1;
  }
  return lo;
}

constexpr void cdeboor4(double u, const float* t, int s, double* N) {
  double left[4] = {}, right[4] = {};
  N[0] = 1.0; N[1] = 0.0; N[2] = 0.0; N[3] = 0.0;
  for (int d = 1; d <= 3; ++d) {
    left[d]  = u - (double)t[s + 1 - d];
    right[d] = (double)t[s + d] - u;
    double saved = 0.0;
    for (int r = 0; r < d; ++r) {
      double temp = N[r] / (right[r + 1] + left[d - r]);
      N[r] = saved + right[r + 1] * temp;
      saved = left[d - r] * temp;
    }
    N[d] = saved;
  }
}

constexpr Tables make_tables() {
  Tables T{};
  float x[NN] = {};
  for (int i = 0; i < NN; ++i) x[i] = (float)(-1.0 + (2.0 * i) / 511.0);
  x[0] = -1.0f; x[NN - 1] = 1.0f;
  float t[NN + 4] = {};
  {
    float cs[NN + 1] = {};
    for (int i = 0; i < NN; ++i) cs[i + 1] = cs[i] + x[i];
    for (int i = 0; i < NN - 4; ++i) t[4 + i] = (cs[4 + i] - cs[1 + i]) / 3.0f;
    for (int i = 0; i < 4; ++i) { t[i] = -1.0f; t[NN + i] = 1.0f; }
  }
  double W[NN][7] = {};
  for (int r = 0; r < NN; ++r) {
    double u = (double)x[r];
    int s = cfindspan(u, t);
    double N[4] = {};
    cdeboor4(u, t, s, N);
    for (int dd = 0; dd < 4; ++dd) W[r][s - r + dd] += N[dd];
  }
  for (int r = 0; r < NN; ++r) {
    double rd = 1.0 / W[r][3];
    for (int k = 1; k <= 3; ++k) {
      if (r + k < NN) {
        double l = W[r + k][3 - k] * rd;
        W[r + k][3 - k] = l;
        for (int cc = 1; cc <= 3; ++cc) W[r + k][3 - k + cc] -= l * W[r][3 + cc];
      }
    }
  }
  // truncated inverse band (half-width WH)
  double Gbd[NN][WT] = {};
  double tv[WT] = {};
  for (int pass = 0; pass < 3; ++pass) {
    const int ylo = (pass == 0) ? 0 : (pass == 1) ? 480 : 256;
    const int yhi = (pass == 0) ? 32 : (pass == 1) ? 512 : 257;
    for (int y = ylo; y < yhi; ++y) {
      double wv[21] = {};
      int rend = y + 20; if (rend > NN - 1) rend = NN - 1;
      wv[0] = 1.0;
      for (int r = y + 1; r <= rend; ++r) {
        double acc = 0.0;
        if (r - 1 >= y) acc += W[r][2] * wv[r - 1 - y];
        if (r - 2 >= y) acc += W[r][1] * wv[r - 2 - y];
        if (r - 3 >= y) acc += W[r][0] * wv[r - 3 - y];
        wv[r - y] = -acc;
      }
      double g[33] = {};
      int glo = y - WH; if (glo < 0) glo = 0;
      for (int r = rend; r >= glo; --r) {
        double acc = (r >= y) ? wv[r - y] : 0.0;
        if (r + 1 <= rend) acc -= W[r][4] * g[r + 1 - (y - WH)];
        if (r + 2 <= rend) acc -= W[r][5] * g[r + 2 - (y - WH)];
        if (r + 3 <= rend) acc -= W[r][6] * g[r + 3 - (y - WH)];
        g[r - (y - WH)] = acc / W[r][3];
      }
      if (pass == 2) {
        for (int d = 0; d < WT; ++d) tv[d] = g[2 * WH - d];   // Ainv[256+WH-d][256]
      } else {
        int jlo = y - WH; if (jlo < 0) jlo = 0;
        int jhi = y + WH; if (jhi > NN - 1) jhi = NN - 1;
        for (int j = jlo; j <= jhi; ++j) {
          const bool bdry = (pass == 0) ? (j < 24) : (j >= 488);
          if (bdry) Gbd[j][y - j + WH] = g[j - (y - WH)];
        }
      }
    }
  }
  for (int j = 24; j < 488; ++j)
    for (int d = 0; d < WT; ++d) Gbd[j][d] = tv[d];
  for (int j = 0; j < NN; ++j)
    for (int d = 0; d < WT; ++d) T.Gb[j][d] = (float)Gbd[j][d];
  for (int d = 0; d < WT; ++d)
    for (int j = 0; j < NN; ++j) T.GbT[d][j] = (float)Gbd[j][d];
  // eval-point basis + anchored transposed 8-tap x-filter
  int    s_all[NE] = {};
  double dN[NE][4] = {};
  for (int i = 0; i < NE; ++i) {
    float xe = (float)(-1.0 + (2.0 * i) / 1023.0);
    if (i == 0) xe = -1.0f;
    if (i == NE - 1) xe = 1.0f;
    double u = (double)xe;
    int s = cfindspan(u, t);
    double N[4] = {};
    cdeboor4(u, t, s, N);
    s_all[i] = s;
    for (int k = 0; k < 4; ++k) dN[i][k] = N[k];
    T.espan[i] = s;
    T.ebas[i * 4 + 0] = (float)N[0];
    T.ebas[i * 4 + 1] = (float)N[1];
    T.ebas[i * 4 + 2] = (float)N[2];
    T.ebas[i * 4 + 3] = (float)N[3];
  }
  // W8T[m][x]: out[x] = sum_m W8T[m][x] * CTrow[a8 + m], a8 = (s_all[quad0]-3)&~1.
  // m = s_all[x]-3+k-a8; max = (s(x0)-a8) + drift + 3 <= 4 + 2 ... <= 6 < 8.
  for (int xx = 0; xx < NE; ++xx) {
    const int a8 = (s_all[(xx >> 2) << 2] - 3) & ~1;
    for (int k = 0; k < 4; ++k) {
      const int m = s_all[xx] - 3 + k - a8;
      T.W8T[m][xx] = (float)dN[xx][k];
    }
  }
  // slide bitmask: bit k set iff espan increments at local row k of the tile
  for (int tt = 0; tt < NE / YT; ++tt) {
    unsigned int m = 0u;
    for (int k = 1; k < YT; ++k)
      if (s_all[tt * YT + k] != s_all[tt * YT + k - 1]) m |= (1u << k);
    T.smask[tt] = m;
  }
  return T;
}

__constant__ Tables g_tab = make_tables();

__device__ __forceinline__ unsigned short f2bf(float f) {
  __hip_bfloat16 h = __float2bfloat16(f);              // round-to-nearest-even
  return reinterpret_cast<const unsigned short&>(h);
}

// ------------- K1: 2D banded solve, pipelined stage 1 (R21) + WT=11 -------------
// CT[bc][j][i] (BF16) = sum_{d,e} Gb[i][d]*Gb[j][e]*Z[bc][i-WH+d][j-WH+e]
// 11-tap window for quad lane q: w[q+3 .. q+13] of the 20-float granule
// window based at (quad_base - 8). 2-buffer 1-ahead load pipeline.

__global__ __launch_bounds__(256) void k_solve2d(const float* __restrict__ Z,
                                                 unsigned short* __restrict__ CT) {
  const int it = blockIdx.x * 64;
  const int jt = blockIdx.y * 64;
  const int bc = blockIdx.z;
  const float* __restrict__ src = Z + (size_t)bc * (NN * NN);
  __shared__ float At[64][89];   // stage-1 result TRANSPOSED: At[jc][ii]
  const int tid = threadIdx.x;
  const int q4 = (tid & 15) * 4;    // quad base (jc for stage1, ic for stage2)
  const int iiB = tid >> 4;

  { // stage 1: 11-tap along j, 80 i-rows, pipelined global reads
    float cy[4][WT];
    #pragma unroll
    for (int d = 0; d < WT; ++d)
      #pragma unroll
      for (int q = 0; q < 4; ++q)
        cy[q][d] = g_tab.GbT[d][jt + q4 + q];     // lane-coalesced
    int gj[5];
    #pragma unroll
    for (int e = 0; e < 5; ++e) {
      int c = jt + q4 - 8 + e * 4;                         // 4-aligned granule
      gj[e] = (c < 0) ? 0 : ((c > NN - 4) ? NN - 4 : c);   // clamp: dead granules hit zero taps
    }
    const float* rp[5];
    #pragma unroll
    for (int p = 0; p < 5; ++p) {
      int gi = it - 8 + p * 16 + iiB;
      gi = (gi < 0) ? 0 : ((gi > NN - 1) ? NN - 1 : gi);   // clamp: killed by stage-2 zero taps
      rp[p] = &src[(size_t)gi * NN];
    }
    float wA[20], wB[20];
    #pragma unroll
    for (int e = 0; e < 5; ++e) *(float4*)&wA[e * 4] = *(const float4*)&rp[0][gj[e]];
    #pragma unroll
    for (int e = 0; e < 5; ++e) *(float4*)&wB[e * 4] = *(const float4*)&rp[1][gj[e]];

    auto fmaStore = [&](int p, const float (&w)[20]) {
      float4 a = make_float4(0.f, 0.f, 0.f, 0.f);
      #pragma unroll
      for (int d = 0; d < WT; ++d) {
        a.x += cy[0][d] * w[3 + d];
        a.y += cy[1][d] * w[4 + d];
        a.z += cy[2][d] * w[5 + d];
        a.w += cy[3][d] * w[6 + d];
      }
      const int ii = p * 16 + iiB;
      At[q4 + 0][ii] = a.x;
      At[q4 + 1][ii] = a.y;
      At[q4 + 2][ii] = a.z;
      At[q4 + 3][ii] = a.w;
    };
    fmaStore(0, wA);
    #pragma unroll
    for (int e = 0; e < 5; ++e) *(float4*)&wA[e * 4] = *(const float4*)&rp[2][gj[e]];
    fmaStore(1, wB);
    #pragma unroll
    for (int e = 0; e < 5; ++e) *(float4*)&wB[e * 4] = *(const float4*)&rp[3][gj[e]];
    fmaStore(2, wA);
    #pragma unroll
    for (int e = 0; e < 5; ++e) *(float4*)&wA[e * 4] = *(const float4*)&rp[4][gj[e]];
    fmaStore(3, wB);
    fmaStore(4, wA);
  }
  { // stage 2: 11-tap along i from LDS; coalesced bf16 writes
    float cx[4][WT];
    #pragma unroll
    for (int d = 0; d < WT; ++d)
      #pragma unroll
      for (int q = 0; q < 4; ++q)
        cx[q][d] = g_tab.GbT[d][it + q4 + q];     // lane-coalesced
    __syncthreads();
    unsigned short* __restrict__ dst = CT + (size_t)bc * (NN * NN);
    #pragma unroll 1
    for (int p = 0; p < 4; ++p) {
      const int jc = p * 16 + iiB;
      float w[20];
      #pragma unroll
      for (int e = 0; e < 5; ++e)
        *(float4*)&w[e * 4] = *(const float4*)&At[jc][q4 + e * 4];
      float4 a = make_float4(0.f, 0.f, 0.f, 0.f);
      #pragma unroll
      for (int d = 0; d < WT; ++d) {
        a.x += cx[0][d] * w[3 + d];
        a.y += cx[1][d] * w[4 + d];
        a.z += cx[2][d] * w[5 + d];
        a.w += cx[3][d] * w[6 + d];
      }
      ushort4 o;
      o.x = f2bf(a.x); o.y = f2bf(a.y); o.z = f2bf(a.z); o.w = f2bf(a.w);
      *(ushort4*)&dst[(size_t)(jt + jc) * NN + it + q4] = o;   // 8B aligned
    }
  }
}

// ------------- K2: batched-store sliding-P eval, 8-TAP window -------------
// a8 = (espan[x0]-3)&~1 -> bf16 window starts at dword boundary: 4 scalar
// uint loads + 8 unpack + 32 FMA per unique CT row (was 3x8B + 12 + 48).
// Everything else (slide bitmask, 2-deep prefetch, store bursts) as R19.
// Last-row reads may overrun CT by <=6B into poisoned ws slack: finite
// values (0xAAAA bf16 = -4.6e-13) times EXACT-ZERO taps.

struct Pf { unsigned int q0, q1, q2, q3; };

__global__ __launch_bounds__(256) void k_eval12(const unsigned short* __restrict__ CT,
                                                float* __restrict__ out) {
  const int b = blockIdx.x;                         // 32 y-tiles
  const int ytile = ((b & 7) << 2) | (b >> 3);      // XCD-chunked swizzle (bijective, 32)
  const int y0 = ytile * YT;
  const int bc = blockIdx.y;
  const unsigned short* __restrict__ S = CT + (size_t)bc * (NN * NN);
  const int tid = threadIdx.x;

  const int x0 = tid * 4;
  const int a8 = (g_tab.espan[x0] - 3) & ~1;        // 2-aligned window base
  float tp[4][8];
  #pragma unroll
  for (int m = 0; m < 8; ++m)
    #pragma unroll
    for (int e = 0; e < 4; ++e)
      tp[e][m] = g_tab.W8T[m][x0 + e];              // lane-coalesced

  auto loadRow = [&](int r) -> Pf {
    r = (r > NN - 1) ? NN - 1 : r;                  // clamp (tail prefetches unused)
    const unsigned int* __restrict__ rp =
        (const unsigned int*)&S[(size_t)r * NN + a8];  // dword-aligned (a8 even)
    Pf f;
    f.q0 = rp[0]; f.q1 = rp[1]; f.q2 = rp[2]; f.q3 = rp[3];
    return f;
  };
  auto filt = [&](Pf f) -> v4f {
    float w[8];
    w[0] = __uint_as_float(f.q0 << 16); w[1] = __uint_as_float(f.q0 & 0xffff0000u);
    w[2] = __uint_as_float(f.q1 << 16); w[3] = __uint_as_float(f.q1 & 0xffff0000u);
    w[4] = __uint_as_float(f.q2 << 16); w[5] = __uint_as_float(f.q2 & 0xffff0000u);
    w[6] = __uint_as_float(f.q3 << 16); w[7] = __uint_as_float(f.q3 & 0xffff0000u);
    v4f p;
    #pragma unroll
    for (int e = 0; e < 4; ++e) {
      float s0 = 0.f, s1 = 0.f;
      #pragma unroll
      for (int m = 0; m < 8; m += 2) {
        s0 += tp[e][m]     * w[m];
        s1 += tp[e][m + 1] * w[m + 1];
      }
      p[e] = s0 + s1;
    }
    return p;
  };

  int prev = g_tab.espan[y0];
  Pf f0 = loadRow(prev - 3), f1 = loadRow(prev - 2),
     f2 = loadRow(prev - 1), f3 = loadRow(prev);
  Pf pfA = loadRow(prev + 1), pfB = loadRow(prev + 2);
  v4f P0 = filt(f0), P1 = filt(f1), P2 = filt(f2), P3 = filt(f3);
  const unsigned int smask = g_tab.smask[ytile];    // SGPR slide schedule

  float* __restrict__ O0 = out + ((size_t)bc * NE + y0) * NE + x0;
  #pragma unroll 1
  for (int bb = 0; bb < YT / 8; ++bb) {
    v4f o[8];
    #pragma unroll
    for (int r = 0; r < 8; ++r) {
      const int k = bb * 8 + r;
      if (smask & (1u << k)) {                      // slide: consume prefetched row
        P0 = P1; P1 = P2; P2 = P3;
        P3 = filt(pfA);
        pfA = pfB;
        prev += 1;
        pfB = loadRow(prev + 2);                    // refill pipeline
      }
      const float4 wy = *(const float4*)&g_tab.ebas[(y0 + k) * 4];
      #pragma unroll
      for (int e = 0; e < 4; ++e)
        o[r][e] = wy.x * P0[e] + wy.y * P1[e] + wy.z * P2[e] + wy.w * P3[e];
    }
    #pragma unroll
    for (int r = 0; r < 8; ++r)
      *(v4f*)&O0[(size_t)(bb * 8 + r) * NE] = o[r]; // burst: hazard once per 8 stores
  }
}

// ---------------- host launcher ----------------

extern "C" void kernel_launch(void* const* d_in, const int* in_sizes, int n_in,
                              void* d_out, int out_size, void* d_ws, size_t ws_size,
                              hipStream_t stream) {
  (void)in_sizes; (void)n_in; (void)out_size; (void)ws_size;
  const float* Z = (const float*)d_in[0];
  float* out = (float*)d_out;
  unsigned short* CT = (unsigned short*)d_ws;   // 32 MB bf16 coefficients

  k_solve2d<<<dim3(8, 8, NBC),    256, 0, stream>>>(Z,  CT);   // pipelined 2D banded solve
  k_eval12 <<<dim3(NE / YT, NBC), 256, 0, stream>>>(CT, out);  // 8-tap batched-store eval
}